// Round 5
// baseline (86.576 us; speedup 1.0000x reference)
//
#include <hip/hip_runtime.h>

#define IN_FLAT 1024
#define BATCH   512
#define NEURONS 4096
#define FOCUS   64

// LDS layout (bytes)
#define BF32_PITCH 68                       // f32 elems per B-accum row (68%32=4 -> spread banks)
#define A16_BASE   17408                    // 64*68*4 bytes of f32 B-accum
#define B16_BASE   (17408 + 8192)
#define LDS_TOTAL  (17408 + 8192 + 8192)    // 33792 B

typedef __bf16 bf16x8 __attribute__((ext_vector_type(8)));
typedef float  f32x4  __attribute__((ext_vector_type(4)));

__device__ __forceinline__ unsigned short f32_to_bf16(float f) {
    unsigned int u = __float_as_uint(f);
    unsigned int r = (u + 0x7fffu + ((u >> 16) & 1u)) >> 16;  // RNE
    return (unsigned short)r;
}
__device__ __forceinline__ unsigned int pack2(float a, float b) {
    return (unsigned int)f32_to_bf16(a) | ((unsigned int)f32_to_bf16(b) << 16);
}

// One fused kernel: y[b][n] = sum_f x[b, idx[n,f]] * w[n,f] + bias[n]
// via per-block on-the-fly densification: B-tile[n][k] accumulated in LDS f32
// (duplicates summed exactly), converted to swizzled bf16, MFMA against
// bf16 A-tile staged from x. 64x64 block tile, BK=64, 4 waves (32x32 each).
__global__ __launch_bounds__(256) void fused_sparse_gemm_kernel(
        const float* __restrict__ x,
        const int*   __restrict__ idx,
        const float* __restrict__ w,
        const float* __restrict__ bias,
        float*       __restrict__ y) {
    __shared__ char smem[LDS_TOTAL];
    float* Bf32 = reinterpret_cast<float*>(smem);

    // XCD-aware swizzle: 512 blocks, b&7 = xcd; each XCD gets 8 n-tiles x 8 m-tiles
    const int b   = blockIdx.x;
    const int xcd = b & 7, jj = b >> 3;
    const int m0  = (jj & 7) * 64;
    const int n0  = (xcd * 8 + (jj >> 3)) * 64;

    const int tid  = threadIdx.x;
    const int lane = tid & 63;
    const int wv   = tid >> 6;
    const int wr   = wv >> 1, wc = wv & 1;   // wave's 32x32 quadrant

    // ---- load this block's (idx,w): 4096 pairs, 16/thread, vectorized+coalesced
    int   li[16];
    float lw[16];
    {
        const int*   ip = idx + (size_t)n0 * FOCUS + tid * 4;
        const float* wp = w   + (size_t)n0 * FOCUS + tid * 4;
        #pragma unroll
        for (int u = 0; u < 4; ++u) {
            const int4   iv = *reinterpret_cast<const int4*>(ip + u * 1024);
            const float4 wf = *reinterpret_cast<const float4*>(wp + u * 1024);
            li[u*4+0] = iv.x & (IN_FLAT-1);  lw[u*4+0] = wf.x;
            li[u*4+1] = iv.y & (IN_FLAT-1);  lw[u*4+1] = wf.y;
            li[u*4+2] = iv.z & (IN_FLAT-1);  lw[u*4+2] = wf.z;
            li[u*4+3] = iv.w & (IN_FLAT-1);  lw[u*4+3] = wf.w;
        }
    }
    // pair p = u*1024 + tid*4 + j  ->  n_local = u*16 + (tid>>4)
    const int nrow_base = tid >> 4;

    // ---- staging thread mapping: row ar (0..63), 16-elem quarter aq (0..3)
    const int ar = tid >> 2, aq = tid & 3;
    const float* xrow = x + (size_t)(m0 + ar) * IN_FLAT + aq * 16;
    const int   aL0   = ar * 128 + aq * 32;
    const int   swz   = (ar & 7) << 4;
    char* adst0 = smem + A16_BASE + ((aL0     ) ^ swz);
    char* adst1 = smem + A16_BASE + ((aL0 + 16) ^ swz);
    char* bdst0 = smem + B16_BASE + ((aL0     ) ^ swz);
    char* bdst1 = smem + B16_BASE + ((aL0 + 16) ^ swz);
    const float* bsrc = Bf32 + ar * BF32_PITCH + aq * 16;

    f32x4 acc[2][2] = {};

    // prefetch A-tile 0 (16 f32 per thread)
    f32x4 pa0 = *reinterpret_cast<const f32x4*>(xrow + 0);
    f32x4 pa1 = *reinterpret_cast<const f32x4*>(xrow + 4);
    f32x4 pa2 = *reinterpret_cast<const f32x4*>(xrow + 8);
    f32x4 pa3 = *reinterpret_cast<const f32x4*>(xrow + 12);

    for (int kt = 0; kt < IN_FLAT / 64; ++kt) {
        // ---- phase Z: zero B-accum (1088 uint4, linear, conflict-free)
        {
            const uint4 zz{0u, 0u, 0u, 0u};
            uint4* z = reinterpret_cast<uint4*>(smem);
            #pragma unroll
            for (int u = 0; u < 4; ++u) z[u * 256 + tid] = zz;
            if (tid < 64) z[1024 + tid] = zz;
        }
        __syncthreads();
        // ---- phase S: scatter-accumulate matching pairs (avg 1/thread/tile)
        #pragma unroll
        for (int u = 0; u < 4; ++u) {
            #pragma unroll
            for (int j = 0; j < 4; ++j) {
                const int v = li[u*4+j];
                if ((v >> 6) == kt)
                    atomicAdd(&Bf32[(u*16 + nrow_base) * BF32_PITCH + (v & 63)],
                              lw[u*4+j]);
            }
        }
        __syncthreads();
        // ---- phase C: convert B f32->bf16 (swizzled), stage A, prefetch next A
        {
            const f32x4 b0 = *reinterpret_cast<const f32x4*>(bsrc + 0);
            const f32x4 b1 = *reinterpret_cast<const f32x4*>(bsrc + 4);
            const f32x4 b2 = *reinterpret_cast<const f32x4*>(bsrc + 8);
            const f32x4 b3 = *reinterpret_cast<const f32x4*>(bsrc + 12);
            *reinterpret_cast<uint4*>(bdst0) =
                uint4{pack2(b0[0], b0[1]), pack2(b0[2], b0[3]),
                      pack2(b1[0], b1[1]), pack2(b1[2], b1[3])};
            *reinterpret_cast<uint4*>(bdst1) =
                uint4{pack2(b2[0], b2[1]), pack2(b2[2], b2[3]),
                      pack2(b3[0], b3[1]), pack2(b3[2], b3[3])};
            *reinterpret_cast<uint4*>(adst0) =
                uint4{pack2(pa0[0], pa0[1]), pack2(pa0[2], pa0[3]),
                      pack2(pa1[0], pa1[1]), pack2(pa1[2], pa1[3])};
            *reinterpret_cast<uint4*>(adst1) =
                uint4{pack2(pa2[0], pa2[1]), pack2(pa2[2], pa2[3]),
                      pack2(pa3[0], pa3[1]), pack2(pa3[2], pa3[3])};
            const int koff = (kt < 15) ? (kt + 1) * 64 : 0;  // avoid OOB on last iter
            pa0 = *reinterpret_cast<const f32x4*>(xrow + koff + 0);
            pa1 = *reinterpret_cast<const f32x4*>(xrow + koff + 4);
            pa2 = *reinterpret_cast<const f32x4*>(xrow + koff + 8);
            pa3 = *reinterpret_cast<const f32x4*>(xrow + koff + 12);
        }
        __syncthreads();
        // ---- phase M: 8x mfma_f32_16x16x32_bf16 (conflict-free swizzled reads)
        #pragma unroll
        for (int ks = 0; ks < 2; ++ks) {
            const int kb = ks * 64 + ((lane >> 4) << 4);
            bf16x8 af[2], bfr[2];
            #pragma unroll
            for (int fm = 0; fm < 2; ++fm) {
                const int row = wr * 32 + fm * 16 + (lane & 15);
                const int L   = row * 128 + kb;
                af[fm] = *reinterpret_cast<const bf16x8*>(
                    smem + A16_BASE + (L ^ ((row & 7) << 4)));
            }
            #pragma unroll
            for (int fn = 0; fn < 2; ++fn) {
                const int row = wc * 32 + fn * 16 + (lane & 15);
                const int L   = row * 128 + kb;
                bfr[fn] = *reinterpret_cast<const bf16x8*>(
                    smem + B16_BASE + (L ^ ((row & 7) << 4)));
            }
            #pragma unroll
            for (int fm = 0; fm < 2; ++fm)
                #pragma unroll
                for (int fn = 0; fn < 2; ++fn)
                    acc[fm][fn] = __builtin_amdgcn_mfma_f32_16x16x32_bf16(
                        af[fm], bfr[fn], acc[fm][fn], 0, 0, 0);
        }
        // no barrier needed here: next phase Z touches only Bf32 region;
        // A16/B16 are only overwritten after two more barriers.
    }

    // ---- epilogue: C/D layout col=lane&15, row=(lane>>4)*4+reg
    const int nbase = n0 + wc * 32 + (lane & 15);
    const int mbase = m0 + wr * 32 + ((lane >> 4) << 2);
    #pragma unroll
    for (int fn = 0; fn < 2; ++fn) {
        const float bv = bias[nbase + fn * 16];
        #pragma unroll
        for (int fm = 0; fm < 2; ++fm) {
            #pragma unroll
            for (int jr = 0; jr < 4; ++jr) {
                y[(size_t)(mbase + fm * 16 + jr) * NEURONS + nbase + fn * 16] =
                    acc[fm][fn][jr] + bv;
            }
        }
    }
}

// ---------- launch: ONE kernel, zero workspace use ----------
extern "C" void kernel_launch(void* const* d_in, const int* in_sizes, int n_in,
                              void* d_out, int out_size, void* d_ws, size_t ws_size,
                              hipStream_t stream) {
    const float* x    = (const float*)d_in[0];
    const int*   idx  = (const int*)  d_in[1];
    const float* w    = (const float*)d_in[2];
    const float* bias = (const float*)d_in[3];
    float*       y    = (float*)d_out;

    fused_sparse_gemm_kernel<<<(BATCH / 64) * (NEURONS / 64), 256, 0, stream>>>(
        x, idx, w, bias, y);
}